// Round 12
// baseline (1598.333 us; speedup 1.0000x reference)
//
#include <hip/hip_runtime.h>
#include <hip/hip_fp16.h>
#include <cstdint>

#define BATCH 256
#define SEQ   2048
#define IN_DIM 4
#define HID   256
#define G4    1024   // 4*HID

// ---------- types ----------
typedef int   i32x8 __attribute__((ext_vector_type(8)));
typedef float f32x4 __attribute__((ext_vector_type(4)));

union U328 { i32x8 v; uint4 q[2]; };

#define LOG2E   1.442695041f
#define SG_SIG  (-1.442695041f)   // sigmoid gates: exp2(-z*log2e)
#define SG_TANH (2.885390082f)    // tanh gate: exp2(2z*log2e)

__device__ __forceinline__ float rcp_(float x) {
#if __has_builtin(__builtin_amdgcn_rcpf)
    return __builtin_amdgcn_rcpf(x);
#else
    return 1.0f / x;
#endif
}
__device__ __forceinline__ float exp2_(float x) {
#if __has_builtin(__builtin_amdgcn_exp2f)
    return __builtin_amdgcn_exp2f(x);
#else
    return exp2f(x);
#endif
}
__device__ __forceinline__ float sigmoidf_(float x) {
    return rcp_(1.0f + exp2_(-LOG2E * x));
}
__device__ __forceinline__ float tanhf_(float x) {
    return 1.0f - 2.0f * rcp_(exp2_(2.0f * LOG2E * x) + 1.0f);
}

// OCP e4m3fn encode (RNE), |a| <= 448 handled via clamp.
__device__ __forceinline__ uint32_t enc_e4m3_sw(float a) {
    uint32_t bits = __float_as_uint(a);
    uint32_t s = (bits >> 24) & 0x80u;
    float am = __uint_as_float(bits & 0x7FFFFFFFu);
    if (am < 0.015625f) {
        uint32_t d = (uint32_t)__float2int_rn(am * 512.0f);
        return s | d;
    }
    uint32_t mag = bits & 0x7FFFFFFFu;
    uint32_t lsb = (mag >> 20) & 1u;
    uint32_t r = mag + 0x0007FFFFu + lsb;
    int E = (int)(r >> 23) - 127 + 7;
    uint32_t m3 = (r >> 20) & 7u;
    if (E > 15) { E = 15; m3 = 6u; }
    return s | ((uint32_t)E << 3) | m3;
}

__device__ __forceinline__ uint32_t enc_e4m3(float a) {
#if __has_builtin(__builtin_amdgcn_cvt_pk_fp8_f32)
    return (uint32_t)__builtin_amdgcn_cvt_pk_fp8_f32(a, a, 0, false) & 0xFFu;
#else
    return enc_e4m3_sw(a);
#endif
}

__device__ __forceinline__ uint32_t pack4_e4m3(float v0, float v1, float v2, float v3) {
#if __has_builtin(__builtin_amdgcn_cvt_pk_fp8_f32)
    int r = __builtin_amdgcn_cvt_pk_fp8_f32(v0, v1, 0, false);
    r = __builtin_amdgcn_cvt_pk_fp8_f32(v2, v3, r, true);
    return (uint32_t)r;
#else
    return enc_e4m3_sw(v0) | (enc_e4m3_sw(v1) << 8) |
           (enc_e4m3_sw(v2) << 16) | (enc_e4m3_sw(v3) << 24);
#endif
}

// ---------- ws layout (bytes) ----------
#define OFF_BIAS  262144
#define OFF_CONVF 266240
#define OFF_KSIM  267264
#define OFF_HOUT  268288

// e8m0 scales: uniform -> byte-select / operand-order provably irrelevant
#define SCALE_H 0x7F7F7F7Fu   // 2^0
#define SCALE_W 0x7B7B7B7Bu   // 2^-4 (weights pre-scaled x16)

// ---------- prep: fp8 MX B-fragments (Whh^T x16 x gate-fold) + bias ----------
// Layout identical to R7/R9/R11 (verified). Per-gate scale fold:
//   gates i,f,o: weights x (-log2e); gate g: x (2*log2e).
__global__ void prep_kernel(const float* __restrict__ Whh,
                            const float* __restrict__ bih,
                            const float* __restrict__ bhh,
                            uint32_t* __restrict__ wfragP,
                            float* __restrict__ bias) {
    int gid = blockIdx.x * blockDim.x + threadIdx.x;  // 0..65535
    int d    = gid & 7;
    int lane = (gid >> 3) & 63;
    int f    = (gid >> 9) & 7;
    int w    = gid >> 12;
    int c  = lane & 15;
    int kb = lane >> 4;
    int g  = f >> 1;
    int kc = f & 1;
    int u   = w * 16 + c;
    int row = g * 256 + u;
    int k0  = kc * 128 + kb * 32 + d * 4;
    const float sg = (g == 2) ? SG_TANH : SG_SIG;
    const float sc = 16.0f * sg;
    const float* src = Whh + (size_t)row * HID + k0;
    uint32_t p = pack4_e4m3(src[0] * sc, src[1] * sc, src[2] * sc, src[3] * sc);
    wfragP[(size_t)gid] = p;

    if (gid < G4) bias[gid] = bih[gid] + bhh[gid];
}

// ---------- features: conv mean + RBF kernel sim ----------
__global__ void feat_kernel(const float* __restrict__ x,
                            const float* __restrict__ conv_w,
                            const float* __restrict__ conv_b,
                            float* __restrict__ convf,
                            float* __restrict__ ksim) {
    int b = blockIdx.x, t = threadIdx.x;  // 256 threads
    const float4* xb = (const float4*)(x + (size_t)b * SEQ * IN_DIM);
    float cw0 = conv_w[0], cw1 = conv_w[1], cw2 = conv_w[2], cw3 = conv_w[3];
    float cb = conv_b[0];
    float s_sig = 0.f, s_sq = 0.f;
#pragma unroll
    for (int k = 0; k < 8; ++k) {
        int s = t + k * 256;
        float4 v = xb[s];
        float d = v.x * cw0 + v.y * cw1 + v.z * cw2 + v.w * cw3 + cb;
        s_sig += sigmoidf_(d);
        s_sq  += v.x * v.x + v.y * v.y + v.z * v.z + v.w * v.w;
    }
    __shared__ float sA[256], sB[256];
    sA[t] = s_sig; sB[t] = s_sq;
    __syncthreads();
    for (int off = 128; off > 0; off >>= 1) {
        if (t < off) { sA[t] += sA[t + off]; sB[t] += sB[t + off]; }
        __syncthreads();
    }
    if (t == 0) {
        convf[b] = sA[0] * (1.0f / 2048.0f);
        ksim[b]  = __expf(-sB[0]);
    }
}

// ---------- LSTM recurrence: MX-fp8 MFMA + per-grp gate specialization ------
// R12 = R11 (best verified kernel) + three surgical edits on the serial
// epilogue chain (PMC: step = 1127 MFMA + 923 VALU, sum 101% -> zero
// overlap, chain-latency matters):
//  1. q16/q32/q48 all shuffled INDEPENDENTLY from pown (q48 = shfl_xor 48)
//     -> the 2-deep shuffle chain (80 cyc exposed) becomes 1-deep (~40).
//  2. xz(s+1) computation placed BETWEEN MFMA issue and acc drains: ~30
//     MFMA-independent VALU ops explicitly fill the matrix-pipe shadow.
//  3. x(s+1) global load hoisted to the very top of the loop body.
#define HB0_DW  0
#define HB1_DW  64
#define SMEM_DW 128   // 512 B

__global__ __launch_bounds__(1024, 4)
void recur_kernel(const float* __restrict__ x,
                  const float* __restrict__ Wih,
                  const uint32_t* __restrict__ wfragP,
                  const float* __restrict__ bias,
                  float* __restrict__ h_out) {
    extern __shared__ uint32_t smem[];
    uint32_t* hb0 = smem + HB0_DW;            // 256 fp8 bytes
    uint32_t* hb1 = smem + HB1_DW;

    const int b = blockIdx.x;
    const int t = threadIdx.x;
    const int lane = t & 63;
    const int w = t >> 6;        // 0..15
    const int cl = lane & 15;
    const int grp = lane >> 4;   // row-group == this lane's gate
    const int uA = w * 16 + cl;

    // all 8 weight fragments -> 8-reg tuples (verified load pattern)
    U328 rf[8];
    {
        const uint32_t* base = wfragP + (size_t)w * 4096 + (size_t)lane * 8;
#pragma unroll
        for (int f = 0; f < 8; ++f) {
            rf[f].q[0] = *(const uint4*)(base + f * 512);
            rf[f].q[1] = *(const uint4*)(base + f * 512 + 4);
        }
    }
#pragma unroll
    for (int f = 0; f < 8; ++f) asm volatile("" : "+v"(rf[f].v));

    if (t < 64) hb0[t] = 0u;   // h = 0 (fp8 zeros)

    // per-lane xz state: ONLY this lane's gate row (grp), log2e-folded
    const float sg = (grp == 2) ? SG_TANH : SG_SIG;
    const float4 wv_raw = ((const float4*)Wih)[grp * 256 + uA];
    const float wvx = wv_raw.x * sg, wvy = wv_raw.y * sg,
                wvz = wv_raw.z * sg, wvw = wv_raw.w * sg;
    const float bs = bias[grp * 256 + uA] * sg;

    const float4* xb = (const float4*)(x + (size_t)b * SEQ * IN_DIM);

    // xz(0); carried in a register across iterations
    float xz;
    {
        const float4 x0 = xb[0];
        xz = bs + x0.x * wvx + x0.y * wvy + x0.z * wvz + x0.w * wvw;
    }

    float cA = 0.f, hA = 0.f;

    __syncthreads();

    uint32_t* hr = hb0; uint32_t* hw = hb1;

    const f32x4 z4 = (f32x4){0.f, 0.f, 0.f, 0.f};
    const bool b0 = (grp & 1) != 0;
    const bool b1 = (grp & 2) != 0;
    const bool isg = (grp == 2);

    for (int s = 0; s < SEQ; ++s) {
        // (3) x(s+1) global load at the very top: max latency cover
        const int sn = (s + 1 < SEQ) ? s + 1 : SEQ - 1;
        const float4 xn = xb[sn];

        const char* hrb = (const char*)hr;
        U328 hk0, hk1;
        hk0.q[0] = *(const uint4*)(hrb + grp * 32);
        hk0.q[1] = *(const uint4*)(hrb + grp * 32 + 16);
        hk1.q[0] = *(const uint4*)(hrb + 128 + grp * 32);
        hk1.q[1] = *(const uint4*)(hrb + 128 + grp * 32 + 16);

        // ---- 8 independent MFMAs, issued as one block (verified) ----
        f32x4 t0 = __builtin_amdgcn_mfma_scale_f32_16x16x128_f8f6f4(
            hk0.v, rf[0].v, z4, 0, 0, 0, SCALE_H, 0, SCALE_W);
        f32x4 t1 = __builtin_amdgcn_mfma_scale_f32_16x16x128_f8f6f4(
            hk1.v, rf[1].v, z4, 0, 0, 0, SCALE_H, 0, SCALE_W);
        f32x4 t2 = __builtin_amdgcn_mfma_scale_f32_16x16x128_f8f6f4(
            hk0.v, rf[2].v, z4, 0, 0, 0, SCALE_H, 0, SCALE_W);
        f32x4 t3 = __builtin_amdgcn_mfma_scale_f32_16x16x128_f8f6f4(
            hk1.v, rf[3].v, z4, 0, 0, 0, SCALE_H, 0, SCALE_W);
        f32x4 t4 = __builtin_amdgcn_mfma_scale_f32_16x16x128_f8f6f4(
            hk0.v, rf[4].v, z4, 0, 0, 0, SCALE_H, 0, SCALE_W);
        f32x4 t5 = __builtin_amdgcn_mfma_scale_f32_16x16x128_f8f6f4(
            hk1.v, rf[5].v, z4, 0, 0, 0, SCALE_H, 0, SCALE_W);
        f32x4 t6 = __builtin_amdgcn_mfma_scale_f32_16x16x128_f8f6f4(
            hk0.v, rf[6].v, z4, 0, 0, 0, SCALE_H, 0, SCALE_W);
        f32x4 t7 = __builtin_amdgcn_mfma_scale_f32_16x16x128_f8f6f4(
            hk1.v, rf[7].v, z4, 0, 0, 0, SCALE_H, 0, SCALE_W);

        // (2) xz(s+1): MFMA-independent work in the matrix-pipe shadow
        const float xz_next = bs + xn.x * wvx + xn.y * wvy
                                 + xn.z * wvz + xn.w * wvw;

        // ---- drain ONLY this grp's gate (6 cndmask selects) ----
        // tuples: (t0,t1)=i (t2,t3)=f (t4,t5)=g (t6,t7)=o
        float za = b0 ? t2[0] : t0[0];
        float zb = b0 ? t6[0] : t4[0];
        float zc = b1 ? zb : za;          // kc0 partial for gate grp
        float zd = b0 ? t3[0] : t1[0];
        float ze = b0 ? t7[0] : t5[0];
        float zf_ = b1 ? ze : zd;         // kc1 partial
        const float zp = zc + zf_ + xz;   // z' (log2e- & sign-folded)

        // ---- ONE nonlinearity per lane ----
        const float p = rcp_(1.0f + exp2_(zp));
        const float pown = isg ? 1.0f - 2.0f * p : p;  // tanh for g, sigmoid else

        // (1) gather 4 gates with 3 INDEPENDENT shuffles (1-deep chain)
        const float q16 = __shfl_xor(pown, 16);
        const float q32 = __shfl_xor(pown, 32);
        const float q48 = __shfl_xor(pown, 48);
        // valid on grp0 (lane<16): pi=pown, pf=q16, pg=q32, po=q48
        cA = q16 * cA + pown * q32;
        hA = q48 * tanhf_(cA);

        xz = xz_next;

        // h(s+1) as fp8: grp0 lanes write (others' cA/hA are dead values)
        if (lane < 16) {
            ((unsigned char*)hw)[uA] = (unsigned char)enc_e4m3(hA);
        }
        __syncthreads();   // the ONLY barrier per step
        uint32_t* tp = hr; hr = hw; hw = tp;
    }

    if (lane < 16) h_out[b * HID + uA] = hA;
}

// ---------- head: fc + relu + out + softmax ----------
__global__ void head_kernel(const float* __restrict__ fc_w,
                            const float* __restrict__ fc_b,
                            const float* __restrict__ out_w,
                            const float* __restrict__ out_b,
                            const float* __restrict__ convf,
                            const float* __restrict__ ksim,
                            const float* __restrict__ h_out,
                            float* __restrict__ out) {
    int b = blockIdx.x, j = threadIdx.x;  // 256 threads
    const float* hrow = h_out + b * HID;
    const float* w = fc_w + j * (HID + 2);
    float acc = fc_b[j] + w[0] * convf[b] + w[HID + 1] * ksim[b];
#pragma unroll 8
    for (int k = 0; k < HID; ++k) acc += w[1 + k] * hrow[k];
    float hid = fmaxf(acc, 0.f);
    __shared__ float r0[256], r1[256];
    r0[j] = hid * out_w[j];
    r1[j] = hid * out_w[HID + j];
    __syncthreads();
    for (int off = 128; off > 0; off >>= 1) {
        if (j < off) { r0[j] += r0[j + off]; r1[j] += r1[j + off]; }
        __syncthreads();
    }
    if (j == 0) {
        float l0 = r0[0] + out_b[0];
        float l1 = r1[0] + out_b[1];
        float m = fmaxf(l0, l1);
        float e0 = __expf(l0 - m), e1 = __expf(l1 - m);
        float inv = 1.0f / (e0 + e1);
        out[b * 2 + 0] = e0 * inv;
        out[b * 2 + 1] = e1 * inv;
    }
}

// ---------- launch ----------
extern "C" void kernel_launch(void* const* d_in, const int* in_sizes, int n_in,
                              void* d_out, int out_size, void* d_ws, size_t ws_size,
                              hipStream_t stream) {
    const float* x      = (const float*)d_in[0];
    const float* conv_w = (const float*)d_in[1];
    const float* conv_b = (const float*)d_in[2];
    const float* Wih    = (const float*)d_in[3];
    const float* Whh    = (const float*)d_in[4];
    const float* bih    = (const float*)d_in[5];
    const float* bhh    = (const float*)d_in[6];
    const float* fcw    = (const float*)d_in[7];
    const float* fcb    = (const float*)d_in[8];
    const float* outw   = (const float*)d_in[9];
    const float* outb   = (const float*)d_in[10];
    float* out = (float*)d_out;

    uint8_t* ws = (uint8_t*)d_ws;
    uint32_t* wfragP = (uint32_t*)ws;
    float* bias  = (float*)(ws + OFF_BIAS);
    float* convf = (float*)(ws + OFF_CONVF);
    float* ksim  = (float*)(ws + OFF_KSIM);
    float* h_out = (float*)(ws + OFF_HOUT);

    prep_kernel<<<256, 256, 0, stream>>>(Whh, bih, bhh, wfragP, bias);
    feat_kernel<<<BATCH, 256, 0, stream>>>(x, conv_w, conv_b, convf, ksim);

    const size_t smem_bytes = (size_t)SMEM_DW * 4;  // 512 B
    recur_kernel<<<BATCH, 1024, smem_bytes, stream>>>(x, Wih, wfragP, bias, h_out);

    head_kernel<<<BATCH, 256, 0, stream>>>(fcw, fcb, outw, outb, convf, ksim, h_out, out);
}

// Round 13
// 1514.362 us; speedup vs baseline: 1.0554x; 1.0554x over previous
//
#include <hip/hip_runtime.h>
#include <hip/hip_fp16.h>
#include <cstdint>

#define BATCH 256
#define SEQ   2048
#define IN_DIM 4
#define HID   256
#define G4    1024   // 4*HID

// ---------- types ----------
typedef int   i32x8 __attribute__((ext_vector_type(8)));
typedef float f32x4 __attribute__((ext_vector_type(4)));

union U328 { i32x8 v; uint4 q[2]; };

#define LOG2E   1.442695041f
#define SG_SIG  (-1.442695041f)   // sigmoid gates: exp2(-z*log2e)
#define SG_TANH (2.885390082f)    // tanh gate: exp2(2z*log2e)

__device__ __forceinline__ float rcp_(float x) {
#if __has_builtin(__builtin_amdgcn_rcpf)
    return __builtin_amdgcn_rcpf(x);
#else
    return 1.0f / x;
#endif
}
__device__ __forceinline__ float exp2_(float x) {
#if __has_builtin(__builtin_amdgcn_exp2f)
    return __builtin_amdgcn_exp2f(x);
#else
    return exp2f(x);
#endif
}
__device__ __forceinline__ float sigmoidf_(float x) {
    return rcp_(1.0f + exp2_(-LOG2E * x));
}
__device__ __forceinline__ float tanhf_(float x) {
    return 1.0f - 2.0f * rcp_(exp2_(2.0f * LOG2E * x) + 1.0f);
}

// xor-16 lane gather, BitMode pattern (xor<<10 | and=0x1F): zero addr VALU
__device__ __forceinline__ float swz16_(float v) {
    return __int_as_float(__builtin_amdgcn_ds_swizzle(__float_as_int(v), 0x401F));
}

// OCP e4m3fn encode (RNE), |a| <= 448 handled via clamp.
__device__ __forceinline__ uint32_t enc_e4m3_sw(float a) {
    uint32_t bits = __float_as_uint(a);
    uint32_t s = (bits >> 24) & 0x80u;
    float am = __uint_as_float(bits & 0x7FFFFFFFu);
    if (am < 0.015625f) {
        uint32_t d = (uint32_t)__float2int_rn(am * 512.0f);
        return s | d;
    }
    uint32_t mag = bits & 0x7FFFFFFFu;
    uint32_t lsb = (mag >> 20) & 1u;
    uint32_t r = mag + 0x0007FFFFu + lsb;
    int E = (int)(r >> 23) - 127 + 7;
    uint32_t m3 = (r >> 20) & 7u;
    if (E > 15) { E = 15; m3 = 6u; }
    return s | ((uint32_t)E << 3) | m3;
}

__device__ __forceinline__ uint32_t enc_e4m3(float a) {
#if __has_builtin(__builtin_amdgcn_cvt_pk_fp8_f32)
    return (uint32_t)__builtin_amdgcn_cvt_pk_fp8_f32(a, a, 0, false) & 0xFFu;
#else
    return enc_e4m3_sw(a);
#endif
}

__device__ __forceinline__ uint32_t pack4_e4m3(float v0, float v1, float v2, float v3) {
#if __has_builtin(__builtin_amdgcn_cvt_pk_fp8_f32)
    int r = __builtin_amdgcn_cvt_pk_fp8_f32(v0, v1, 0, false);
    r = __builtin_amdgcn_cvt_pk_fp8_f32(v2, v3, r, true);
    return (uint32_t)r;
#else
    return enc_e4m3_sw(v0) | (enc_e4m3_sw(v1) << 8) |
           (enc_e4m3_sw(v2) << 16) | (enc_e4m3_sw(v3) << 24);
#endif
}

// ---------- ws layout (bytes) ----------
#define OFF_BIAS  262144
#define OFF_CONVF 266240
#define OFF_KSIM  267264
#define OFF_HOUT  268288

// e8m0 scales: uniform -> byte-select / operand-order provably irrelevant
#define SCALE_H 0x7F7F7F7Fu   // 2^0
#define SCALE_W 0x7B7B7B7Bu   // 2^-4 (weights pre-scaled x16)

// ---------- prep: fp8 MX B-fragments (Whh^T x16 x gate-fold) + bias ----------
// Layout identical to R7/R9/R11 (verified). Per-gate scale fold:
//   gates i,f,o: weights x (-log2e); gate g: x (2*log2e).
__global__ void prep_kernel(const float* __restrict__ Whh,
                            const float* __restrict__ bih,
                            const float* __restrict__ bhh,
                            uint32_t* __restrict__ wfragP,
                            float* __restrict__ bias) {
    int gid = blockIdx.x * blockDim.x + threadIdx.x;  // 0..65535
    int d    = gid & 7;
    int lane = (gid >> 3) & 63;
    int f    = (gid >> 9) & 7;
    int w    = gid >> 12;
    int c  = lane & 15;
    int kb = lane >> 4;
    int g  = f >> 1;
    int kc = f & 1;
    int u   = w * 16 + c;
    int row = g * 256 + u;
    int k0  = kc * 128 + kb * 32 + d * 4;
    const float sg = (g == 2) ? SG_TANH : SG_SIG;
    const float sc = 16.0f * sg;
    const float* src = Whh + (size_t)row * HID + k0;
    uint32_t p = pack4_e4m3(src[0] * sc, src[1] * sc, src[2] * sc, src[3] * sc);
    wfragP[(size_t)gid] = p;

    if (gid < G4) bias[gid] = bih[gid] + bhh[gid];
}

// ---------- features: conv mean + RBF kernel sim ----------
__global__ void feat_kernel(const float* __restrict__ x,
                            const float* __restrict__ conv_w,
                            const float* __restrict__ conv_b,
                            float* __restrict__ convf,
                            float* __restrict__ ksim) {
    int b = blockIdx.x, t = threadIdx.x;  // 256 threads
    const float4* xb = (const float4*)(x + (size_t)b * SEQ * IN_DIM);
    float cw0 = conv_w[0], cw1 = conv_w[1], cw2 = conv_w[2], cw3 = conv_w[3];
    float cb = conv_b[0];
    float s_sig = 0.f, s_sq = 0.f;
#pragma unroll
    for (int k = 0; k < 8; ++k) {
        int s = t + k * 256;
        float4 v = xb[s];
        float d = v.x * cw0 + v.y * cw1 + v.z * cw2 + v.w * cw3 + cb;
        s_sig += sigmoidf_(d);
        s_sq  += v.x * v.x + v.y * v.y + v.z * v.z + v.w * v.w;
    }
    __shared__ float sA[256], sB[256];
    sA[t] = s_sig; sB[t] = s_sq;
    __syncthreads();
    for (int off = 128; off > 0; off >>= 1) {
        if (t < off) { sA[t] += sA[t + off]; sB[t] += sB[t + off]; }
        __syncthreads();
    }
    if (t == 0) {
        convf[b] = sA[0] * (1.0f / 2048.0f);
        ksim[b]  = __expf(-sB[0]);
    }
}

// ---------- LSTM recurrence: MX-fp8 MFMA + per-grp gate specialization ------
// R13 = R12 + VALU-issue diet (PMC: step 98% packed MFMA 1118 + VALU 891;
// VALU is issue-bound -> remove INSTRUCTIONS, not latency):
//  1. final iteration PEELED -> no per-step clamp on the x(s+1) prefetch.
//  2. xor-16 gate gather via ds_swizzle imm pattern (zero addr VALU).
//  3. pown = fma(p, m, b) with hoisted per-lane constants (1 op).
//  4. zero C-tuple pinned via asm: no per-step accvgpr re-seeding.
#define HB0_DW  0
#define HB1_DW  64
#define SMEM_DW 128   // 512 B

__global__ __launch_bounds__(1024, 4)
void recur_kernel(const float* __restrict__ x,
                  const float* __restrict__ Wih,
                  const uint32_t* __restrict__ wfragP,
                  const float* __restrict__ bias,
                  float* __restrict__ h_out) {
    extern __shared__ uint32_t smem[];
    uint32_t* hb0 = smem + HB0_DW;            // 256 fp8 bytes
    uint32_t* hb1 = smem + HB1_DW;

    const int b = blockIdx.x;
    const int t = threadIdx.x;
    const int lane = t & 63;
    const int w = t >> 6;        // 0..15
    const int cl = lane & 15;
    const int grp = lane >> 4;   // row-group == this lane's gate
    const int uA = w * 16 + cl;

    // all 8 weight fragments -> 8-reg tuples (verified load pattern)
    U328 rf[8];
    {
        const uint32_t* base = wfragP + (size_t)w * 4096 + (size_t)lane * 8;
#pragma unroll
        for (int f = 0; f < 8; ++f) {
            rf[f].q[0] = *(const uint4*)(base + f * 512);
            rf[f].q[1] = *(const uint4*)(base + f * 512 + 4);
        }
    }
#pragma unroll
    for (int f = 0; f < 8; ++f) asm volatile("" : "+v"(rf[f].v));

    if (t < 64) hb0[t] = 0u;   // h = 0 (fp8 zeros)

    // per-lane xz state: ONLY this lane's gate row (grp), log2e-folded
    const float sg = (grp == 2) ? SG_TANH : SG_SIG;
    const float4 wv_raw = ((const float4*)Wih)[grp * 256 + uA];
    const float wvx = wv_raw.x * sg, wvy = wv_raw.y * sg,
                wvz = wv_raw.z * sg, wvw = wv_raw.w * sg;
    const float bs = bias[grp * 256 + uA] * sg;

    // hoisted nonlinearity constants: pown = fma(p, nl_m, nl_b)
    const bool isg = (grp == 2);
    const float nl_m = isg ? -2.0f : 1.0f;
    const float nl_b = isg ?  1.0f : 0.0f;
    const bool b0 = (grp & 1) != 0;
    const bool b1 = (grp & 2) != 0;

    const float4* xb = (const float4*)(x + (size_t)b * SEQ * IN_DIM);

    // xz(0); carried in a register across iterations
    float xz;
    {
        const float4 x0 = xb[0];
        xz = bs + x0.x * wvx + x0.y * wvy + x0.z * wvz + x0.w * wvw;
    }

    float cA = 0.f, hA = 0.f;

    __syncthreads();

    uint32_t* hr = hb0; uint32_t* hw = hb1;

    // pinned read-only zero C-tuple: compiler cannot re-materialize seeds
    f32x4 z4 = (f32x4){0.f, 0.f, 0.f, 0.f};
    asm volatile("" : "+v"(z4));

    for (int s = 0; s < SEQ - 1; ++s) {
        // x(s+1) prefetch, UNCONDITIONAL (final iteration peeled below)
        const float4 xn = xb[s + 1];

        const char* hrb = (const char*)hr;
        U328 hk0, hk1;
        hk0.q[0] = *(const uint4*)(hrb + grp * 32);
        hk0.q[1] = *(const uint4*)(hrb + grp * 32 + 16);
        hk1.q[0] = *(const uint4*)(hrb + 128 + grp * 32);
        hk1.q[1] = *(const uint4*)(hrb + 128 + grp * 32 + 16);

        // ---- 8 independent MFMAs, issued as one block (verified) ----
        f32x4 t0 = __builtin_amdgcn_mfma_scale_f32_16x16x128_f8f6f4(
            hk0.v, rf[0].v, z4, 0, 0, 0, SCALE_H, 0, SCALE_W);
        f32x4 t1 = __builtin_amdgcn_mfma_scale_f32_16x16x128_f8f6f4(
            hk1.v, rf[1].v, z4, 0, 0, 0, SCALE_H, 0, SCALE_W);
        f32x4 t2 = __builtin_amdgcn_mfma_scale_f32_16x16x128_f8f6f4(
            hk0.v, rf[2].v, z4, 0, 0, 0, SCALE_H, 0, SCALE_W);
        f32x4 t3 = __builtin_amdgcn_mfma_scale_f32_16x16x128_f8f6f4(
            hk1.v, rf[3].v, z4, 0, 0, 0, SCALE_H, 0, SCALE_W);
        f32x4 t4 = __builtin_amdgcn_mfma_scale_f32_16x16x128_f8f6f4(
            hk0.v, rf[4].v, z4, 0, 0, 0, SCALE_H, 0, SCALE_W);
        f32x4 t5 = __builtin_amdgcn_mfma_scale_f32_16x16x128_f8f6f4(
            hk1.v, rf[5].v, z4, 0, 0, 0, SCALE_H, 0, SCALE_W);
        f32x4 t6 = __builtin_amdgcn_mfma_scale_f32_16x16x128_f8f6f4(
            hk0.v, rf[6].v, z4, 0, 0, 0, SCALE_H, 0, SCALE_W);
        f32x4 t7 = __builtin_amdgcn_mfma_scale_f32_16x16x128_f8f6f4(
            hk1.v, rf[7].v, z4, 0, 0, 0, SCALE_H, 0, SCALE_W);

        // xz(s+1): MFMA-independent work in the matrix-pipe shadow
        const float xz_next = bs + xn.x * wvx + xn.y * wvy
                                 + xn.z * wvz + xn.w * wvw;

        // ---- drain ONLY this grp's gate (6 cndmask selects) ----
        float za = b0 ? t2[0] : t0[0];
        float zb = b0 ? t6[0] : t4[0];
        float zc = b1 ? zb : za;
        float zd = b0 ? t3[0] : t1[0];
        float ze = b0 ? t7[0] : t5[0];
        float zf_ = b1 ? ze : zd;
        const float zp = zc + zf_ + xz;

        // ---- ONE nonlinearity per lane (single fma select) ----
        const float p = rcp_(1.0f + exp2_(zp));
        const float pown = __builtin_fmaf(p, nl_m, nl_b);

        // ---- gather 4 gates: swizzle(16) + 2 independent shuffles ----
        const float q16 = swz16_(pown);
        const float q32 = __shfl_xor(pown, 32);
        const float q48 = __shfl_xor(pown, 48);
        // valid on grp0 (lane<16): pi=pown, pf=q16, pg=q32, po=q48
        cA = q16 * cA + pown * q32;
        hA = q48 * tanhf_(cA);

        xz = xz_next;

        // h(s+1) as fp8: grp0 lanes write
        if (lane < 16) {
            ((unsigned char*)hw)[uA] = (unsigned char)enc_e4m3(hA);
        }
        __syncthreads();   // the ONLY barrier per step
        uint32_t* tp = hr; hr = hw; hw = tp;
    }

    // ---- peeled final step: no prefetch, no h-buffer write, no barrier ----
    {
        const char* hrb = (const char*)hr;
        U328 hk0, hk1;
        hk0.q[0] = *(const uint4*)(hrb + grp * 32);
        hk0.q[1] = *(const uint4*)(hrb + grp * 32 + 16);
        hk1.q[0] = *(const uint4*)(hrb + 128 + grp * 32);
        hk1.q[1] = *(const uint4*)(hrb + 128 + grp * 32 + 16);

        f32x4 t0 = __builtin_amdgcn_mfma_scale_f32_16x16x128_f8f6f4(
            hk0.v, rf[0].v, z4, 0, 0, 0, SCALE_H, 0, SCALE_W);
        f32x4 t1 = __builtin_amdgcn_mfma_scale_f32_16x16x128_f8f6f4(
            hk1.v, rf[1].v, z4, 0, 0, 0, SCALE_H, 0, SCALE_W);
        f32x4 t2 = __builtin_amdgcn_mfma_scale_f32_16x16x128_f8f6f4(
            hk0.v, rf[2].v, z4, 0, 0, 0, SCALE_H, 0, SCALE_W);
        f32x4 t3 = __builtin_amdgcn_mfma_scale_f32_16x16x128_f8f6f4(
            hk1.v, rf[3].v, z4, 0, 0, 0, SCALE_H, 0, SCALE_W);
        f32x4 t4 = __builtin_amdgcn_mfma_scale_f32_16x16x128_f8f6f4(
            hk0.v, rf[4].v, z4, 0, 0, 0, SCALE_H, 0, SCALE_W);
        f32x4 t5 = __builtin_amdgcn_mfma_scale_f32_16x16x128_f8f6f4(
            hk1.v, rf[5].v, z4, 0, 0, 0, SCALE_H, 0, SCALE_W);
        f32x4 t6 = __builtin_amdgcn_mfma_scale_f32_16x16x128_f8f6f4(
            hk0.v, rf[6].v, z4, 0, 0, 0, SCALE_H, 0, SCALE_W);
        f32x4 t7 = __builtin_amdgcn_mfma_scale_f32_16x16x128_f8f6f4(
            hk1.v, rf[7].v, z4, 0, 0, 0, SCALE_H, 0, SCALE_W);

        float za = b0 ? t2[0] : t0[0];
        float zb = b0 ? t6[0] : t4[0];
        float zc = b1 ? zb : za;
        float zd = b0 ? t3[0] : t1[0];
        float ze = b0 ? t7[0] : t5[0];
        float zf_ = b1 ? ze : zd;
        const float zp = zc + zf_ + xz;

        const float p = rcp_(1.0f + exp2_(zp));
        const float pown = __builtin_fmaf(p, nl_m, nl_b);

        const float q16 = swz16_(pown);
        const float q32 = __shfl_xor(pown, 32);
        const float q48 = __shfl_xor(pown, 48);
        cA = q16 * cA + pown * q32;
        hA = q48 * tanhf_(cA);
    }

    if (lane < 16) h_out[b * HID + uA] = hA;
}

// ---------- head: fc + relu + out + softmax ----------
__global__ void head_kernel(const float* __restrict__ fc_w,
                            const float* __restrict__ fc_b,
                            const float* __restrict__ out_w,
                            const float* __restrict__ out_b,
                            const float* __restrict__ convf,
                            const float* __restrict__ ksim,
                            const float* __restrict__ h_out,
                            float* __restrict__ out) {
    int b = blockIdx.x, j = threadIdx.x;  // 256 threads
    const float* hrow = h_out + b * HID;
    const float* w = fc_w + j * (HID + 2);
    float acc = fc_b[j] + w[0] * convf[b] + w[HID + 1] * ksim[b];
#pragma unroll 8
    for (int k = 0; k < HID; ++k) acc += w[1 + k] * hrow[k];
    float hid = fmaxf(acc, 0.f);
    __shared__ float r0[256], r1[256];
    r0[j] = hid * out_w[j];
    r1[j] = hid * out_w[HID + j];
    __syncthreads();
    for (int off = 128; off > 0; off >>= 1) {
        if (j < off) { r0[j] += r0[j + off]; r1[j] += r1[j + off]; }
        __syncthreads();
    }
    if (j == 0) {
        float l0 = r0[0] + out_b[0];
        float l1 = r1[0] + out_b[1];
        float m = fmaxf(l0, l1);
        float e0 = __expf(l0 - m), e1 = __expf(l1 - m);
        float inv = 1.0f / (e0 + e1);
        out[b * 2 + 0] = e0 * inv;
        out[b * 2 + 1] = e1 * inv;
    }
}

// ---------- launch ----------
extern "C" void kernel_launch(void* const* d_in, const int* in_sizes, int n_in,
                              void* d_out, int out_size, void* d_ws, size_t ws_size,
                              hipStream_t stream) {
    const float* x      = (const float*)d_in[0];
    const float* conv_w = (const float*)d_in[1];
    const float* conv_b = (const float*)d_in[2];
    const float* Wih    = (const float*)d_in[3];
    const float* Whh    = (const float*)d_in[4];
    const float* bih    = (const float*)d_in[5];
    const float* bhh    = (const float*)d_in[6];
    const float* fcw    = (const float*)d_in[7];
    const float* fcb    = (const float*)d_in[8];
    const float* outw   = (const float*)d_in[9];
    const float* outb   = (const float*)d_in[10];
    float* out = (float*)d_out;

    uint8_t* ws = (uint8_t*)d_ws;
    uint32_t* wfragP = (uint32_t*)ws;
    float* bias  = (float*)(ws + OFF_BIAS);
    float* convf = (float*)(ws + OFF_CONVF);
    float* ksim  = (float*)(ws + OFF_KSIM);
    float* h_out = (float*)(ws + OFF_HOUT);

    prep_kernel<<<256, 256, 0, stream>>>(Whh, bih, bhh, wfragP, bias);
    feat_kernel<<<BATCH, 256, 0, stream>>>(x, conv_w, conv_b, convf, ksim);

    const size_t smem_bytes = (size_t)SMEM_DW * 4;  // 512 B
    recur_kernel<<<BATCH, 1024, smem_bytes, stream>>>(x, Wih, wfragP, bias, h_out);

    head_kernel<<<BATCH, 256, 0, stream>>>(fcw, fcb, outw, outb, convf, ksim, h_out, out);
}